// Round 14
// baseline (305.914 us; speedup 1.0000x reference)
//
#include <hip/hip_runtime.h>
#include <hip/hip_bf16.h>

typedef __bf16 bf16x8 __attribute__((ext_vector_type(8)));
typedef float f32x16 __attribute__((ext_vector_type(16)));

// ============ builder kernels for the item->batch inverted index ============

// U' table (u[b]*h, 1MB, L2-resident) + zero the item counters.
__global__ __launch_bounds__(256) void prep_kernel(
    const int* __restrict__ users, const float* __restrict__ user_emb,
    const float* __restrict__ Hw, int batch, unsigned npad,
    float* __restrict__ Up, unsigned* __restrict__ counts) {
    const int bid = blockIdx.x, t = threadIdx.x;
    if (bid < 64) {
        const int n = batch * 64;
        for (int e = bid * 256 + t; e < n; e += 64 * 256) {
            const int b = e >> 6, d = e & 63;
            Up[e] = user_emb[(size_t)users[b] * 64 + d] * Hw[d];
        }
    } else {
        const unsigned nb = gridDim.x - 64;
        for (unsigned i = (bid - 64) * 256 + t; i <= npad; i += nb * 256)
            counts[i] = 0u;
    }
}

__global__ __launch_bounds__(256) void hist_kernel(
    const int* __restrict__ users, const int* __restrict__ hist,
    int batch, int histL, unsigned* __restrict__ counts) {
    const int n = batch * histL;
    const int stride = gridDim.x * 256;
    for (int e = blockIdx.x * 256 + threadIdx.x; e < n; e += stride) {
        const int b = e / histL, l = e - b * histL;
        const int it = hist[(size_t)users[b] * histL + l];
        atomicAdd(&counts[it], 1u);
    }
}

__global__ __launch_bounds__(256) void bsum_kernel(
    const unsigned* __restrict__ counts, unsigned* __restrict__ btot) {
    const int t = threadIdx.x;
    const unsigned base = blockIdx.x * 1024;
    unsigned s = 0;
    for (int i = t; i < 1024; i += 256) s += counts[base + i];
#pragma unroll
    for (int off = 32; off >= 1; off >>= 1) s += __shfl_xor(s, off, 64);
    __shared__ unsigned r[4];
    if ((t & 63) == 0) r[t >> 6] = s;
    __syncthreads();
    if (t == 0) btot[blockIdx.x] = r[0] + r[1] + r[2] + r[3];
}

__global__ __launch_bounds__(1024) void scan_kernel(
    const unsigned* __restrict__ btot, int nblk, unsigned* __restrict__ boff) {
    const int t = threadIdx.x;
    __shared__ unsigned sh[1024];
    const unsigned v = (t < nblk) ? btot[t] : 0u;
    sh[t] = v;
    __syncthreads();
    for (int off = 1; off < 1024; off <<= 1) {
        const unsigned a = (t >= off) ? sh[t - off] : 0u;
        __syncthreads();
        sh[t] += a;
        __syncthreads();
    }
    if (t < nblk) boff[t] = sh[t] - v;
    if (t == nblk - 1) boff[nblk] = sh[t];
}

__global__ __launch_bounds__(256) void off_kernel(
    const unsigned* __restrict__ counts, const unsigned* __restrict__ boff,
    unsigned npad, unsigned* __restrict__ offsets, unsigned* __restrict__ cursor) {
    const int bid = blockIdx.x, t = threadIdx.x;
    const unsigned i0 = bid * 1024 + t * 4;
    const unsigned c0 = counts[i0], c1 = counts[i0 + 1],
                   c2 = counts[i0 + 2], c3 = counts[i0 + 3];
    const unsigned tot = c0 + c1 + c2 + c3;
    __shared__ unsigned sh[256];
    sh[t] = tot;
    __syncthreads();
    for (int off = 1; off < 256; off <<= 1) {
        const unsigned a = (t >= off) ? sh[t - off] : 0u;
        __syncthreads();
        sh[t] += a;
        __syncthreads();
    }
    const unsigned o = boff[bid] + sh[t] - tot;
    offsets[i0] = o;                 cursor[i0] = o;
    offsets[i0 + 1] = o + c0;        cursor[i0 + 1] = o + c0;
    offsets[i0 + 2] = o + c0 + c1;   cursor[i0 + 2] = o + c0 + c1;
    offsets[i0 + 3] = o + c0 + c1 + c2; cursor[i0 + 3] = o + c0 + c1 + c2;
    if (i0 + 4 == npad) offsets[npad] = boff[gridDim.x];
}

__global__ __launch_bounds__(256) void scatter_kernel(
    const int* __restrict__ users, const int* __restrict__ hist,
    int batch, int histL, unsigned* __restrict__ cursor,
    unsigned* __restrict__ vals) {
    const int n = batch * histL;
    const int stride = gridDim.x * 256;
    for (int e = blockIdx.x * 256 + threadIdx.x; e < n; e += stride) {
        const int b = e / histL, l = e - b * histL;
        const int it = hist[(size_t)users[b] * histL + l];
        const unsigned p = atomicAdd(&cursor[it], 1u);
        vals[p] = (unsigned)b;
    }
}

// ============ gram (+ optional in-stream pos) ===============================
// Lanes 0-31 (kh=0) hold rows kb..kb+7 complete: col c in cur0[j], col c+32
// in cur1[j]; lanes 32-63 the next 8 rows. DOPOS: per row, walk its inverted
// list; dot vs L2-resident U' = 2 FMA + 5 width-32 shfl per entry.
template<bool GATHER, bool DOPOS>
static __device__ __forceinline__ void gram_body(
    const float* __restrict__ emb, const int* __restrict__ idx,
    int nrows, int nwaves_total, int blk,
    const unsigned* __restrict__ offsets, const unsigned* __restrict__ vals,
    const float* __restrict__ Up,
    float* __restrict__ partial, float* __restrict__ ps1, float* __restrict__ ps2,
    float* __restrict__ red, float* __restrict__ rs, int t) {
    const int lane = t & 63, wave = t >> 6;
    const int c = lane & 31, kh = lane >> 5;
    const int wid = blk * 4 + wave;
    const int step = nwaves_total * 16;

    f32x16 g00 = {}, g01 = {}, g11 = {};
    float cur0[8], cur1[8];
    float s1 = 0.f, s2 = 0.f;

    int k0 = wid * 16;
    if (k0 < nrows) {
        const int kb = k0 + kh * 8;
#pragma unroll
        for (int j = 0; j < 8; ++j) {
            const size_t rb = (GATHER ? (size_t)idx[kb + j] : (size_t)(kb + j)) * 64;
            cur0[j] = emb[rb + c];
            cur1[j] = emb[rb + 32 + c];
        }
    }
    for (; k0 < nrows; k0 += step) {
        float nx0[8], nx1[8];
        const int k1 = k0 + step;
        if (k1 < nrows) {                        // prefetch next chunk
            const int kb = k1 + kh * 8;
#pragma unroll
            for (int j = 0; j < 8; ++j) {
                const size_t rb = (GATHER ? (size_t)idx[kb + j] : (size_t)(kb + j)) * 64;
                nx0[j] = emb[rb + c];
                nx1[j] = emb[rb + 32 + c];
            }
        } else {
#pragma unroll
            for (int j = 0; j < 8; ++j) { nx0[j] = 0.f; nx1[j] = 0.f; }
        }
        bf16x8 f0, f1;                           // nrows % 16 == 0 here
#pragma unroll
        for (int j = 0; j < 8; ++j) {
            f0[j] = (__bf16)cur0[j];
            f1[j] = (__bf16)cur1[j];
        }
        g00 = __builtin_amdgcn_mfma_f32_32x32x16_bf16(f0, f0, g00, 0, 0, 0);
        g01 = __builtin_amdgcn_mfma_f32_32x32x16_bf16(f0, f1, g01, 0, 0, 0);
        g11 = __builtin_amdgcn_mfma_f32_32x32x16_bf16(f1, f1, g11, 0, 0, 0);
        if (DOPOS) {
            const int rbase = k0 + kh * 8;
#pragma unroll
            for (int j = 0; j < 8; ++j) {        // static j -> cur[j] stays in regs
                const unsigned o0 = offsets[rbase + j];
                const unsigned o1 = offsets[rbase + j + 1];
                for (unsigned e = o0; e < o1; ++e) {
                    const int b = (int)vals[e];
                    float dd = fmaf(cur0[j], Up[b * 64 + c],
                                    cur1[j] * Up[b * 64 + 32 + c]);
                    dd += __shfl_xor(dd, 1, 32);
                    dd += __shfl_xor(dd, 2, 32);
                    dd += __shfl_xor(dd, 4, 32);
                    dd += __shfl_xor(dd, 8, 32);
                    dd += __shfl_xor(dd, 16, 32);
                    s1 += dd;
                    s2 = fmaf(dd, dd, s2);
                }
            }
        }
#pragma unroll
        for (int j = 0; j < 8; ++j) { cur0[j] = nx0[j]; cur1[j] = nx1[j]; }
    }

    if (DOPOS) {                                 // combine the two half-waves
        s1 += __shfl_xor(s1, 32, 64);
        s2 += __shfl_xor(s2, 32, 64);
    }

    __syncthreads();
    for (int w = 0; w < 4; ++w) {
        if (wave == w) {
#pragma unroll
            for (int r = 0; r < 16; ++r) {
                const int cell = ((r & 3) + 8 * (r >> 2) + 4 * kh) * 32 + c;
                if (w == 0) {
                    red[cell] = g00[r]; red[1024 + cell] = g01[r]; red[2048 + cell] = g11[r];
                } else {
                    red[cell] += g00[r]; red[1024 + cell] += g01[r]; red[2048 + cell] += g11[r];
                }
            }
            if (DOPOS && lane == 0) {
                if (w == 0) { rs[0] = s1; rs[1] = s2; }
                else        { rs[0] += s1; rs[1] += s2; }
            }
        }
        __syncthreads();
    }
    float* outp = partial + (size_t)blk * 3072;
    for (int i = t; i < 3072; i += 256) outp[i] = red[i];
    if (DOPOS && t == 0) { ps1[blk] = rs[0]; ps2[blk] = rs[1]; }
}

// ---- fused heavy kernel: gram+pos | sumsq | user gram ----------------------
__global__ __launch_bounds__(256, 4) void fused_kernel(
    const int* __restrict__ users, const float* __restrict__ user_emb,
    const float* __restrict__ item_emb,
    int n_users, int n_items, int batch,
    int NA, int NSS, int NU,
    const unsigned* __restrict__ offsets, const unsigned* __restrict__ vals,
    const float* __restrict__ Up,
    float* __restrict__ partA, float* __restrict__ partB,
    float* __restrict__ ps1, float* __restrict__ ps2, float* __restrict__ pss) {
    __shared__ float red[3072];
    __shared__ float rs[2];
    const int bid = blockIdx.x, t = threadIdx.x;

    if (bid < NA) {
        gram_body<false, true>(item_emb, nullptr, n_items, NA * 4, bid,
                               offsets, vals, Up, partA, ps1, ps2, red, rs, t);
    } else if (bid < NA + NSS) {                 // ---- sumsq role
        const int cid = bid - NA;
        const int n4 = n_users * 16;
        float s = 0.f;
        for (int i = cid * 256 + t; i < n4; i += NSS * 256) {
            const float4 v = reinterpret_cast<const float4*>(user_emb)[i];
            s = fmaf(v.x, v.x, s); s = fmaf(v.y, v.y, s);
            s = fmaf(v.z, v.z, s); s = fmaf(v.w, v.w, s);
        }
#pragma unroll
        for (int off = 32; off >= 1; off >>= 1) s += __shfl_xor(s, off, 64);
        if ((t & 63) == 0) red[t >> 6] = s;
        __syncthreads();
        if (t == 0) pss[cid] = red[0] + red[1] + red[2] + red[3];
    } else {                                     // ---- user gram role
        gram_body<true, false>(user_emb, users, batch, NU * 4, bid - NA - NSS,
                               nullptr, nullptr, nullptr, partB,
                               nullptr, nullptr, red, rs, t);
    }
}

// ---- stage-1 reduce of gram partials, 8-way partial-dim split --------------
__global__ __launch_bounds__(256) void reduce_gram_kernel(
    const float* __restrict__ pa, int na,
    const float* __restrict__ pb, int nb, float* __restrict__ part2) {
    const int bid = blockIdx.x;
    const int cellblk = bid % 24, seg = bid / 24;
    const int e = cellblk * 256 + threadIdx.x;
    const float* p; int n, ee;
    if (e < 3072) { p = pa; n = na; ee = e; }
    else          { p = pb; n = nb; ee = e - 3072; }
    const int chunk = (n + 7) >> 3;
    const int b0 = seg * chunk;
    int b1 = b0 + chunk; if (b1 > n) b1 = n;
    float s[4] = {0.f, 0.f, 0.f, 0.f};
    int b = b0;
    for (; b + 4 <= b1; b += 4)
#pragma unroll
        for (int u = 0; u < 4; ++u) s[u] += p[(size_t)(b + u) * 3072 + ee];
    for (; b < b1; ++b) s[0] += p[(size_t)b * 3072 + ee];
    part2[(size_t)seg * 6144 + e] = (s[0] + s[1]) + (s[2] + s[3]);
}

// ---- finalize ---------------------------------------------------------------
__global__ __launch_bounds__(1024) void finalize_kernel(
    const float* __restrict__ part2, const float* __restrict__ Hw,
    const float* __restrict__ p1, const float* __restrict__ p2, int npos,
    const float* __restrict__ pss, int nss, float* __restrict__ outp) {
    const int t = threadIdx.x;
    float tsum = 0.f, trace = 0.f, s1 = 0.f, s2 = 0.f, su = 0.f;
    for (int e = t; e < 3072; e += 1024) {
        float gi = 0.f, gu = 0.f;
#pragma unroll
        for (int seg = 0; seg < 8; ++seg) {
            gi += part2[(size_t)seg * 6144 + e];
            gu += part2[(size_t)seg * 6144 + 3072 + e];
        }
        const int tile = e >> 10, r = (e & 1023) >> 5, cc = e & 31;
        const int i = (tile == 2) ? r + 32 : r;
        const int j = (tile == 0) ? cc : cc + 32;
        const float w = (tile == 1) ? 2.0f : 1.0f;
        tsum += w * gi * gu * Hw[i] * Hw[j];
        if (i == j) trace += gi;
    }
    for (int e = t; e < npos; e += 1024) { s1 += p1[e]; s2 += p2[e]; }
    for (int e = t; e < nss; e += 1024) su += pss[e];
#pragma unroll
    for (int off = 32; off >= 1; off >>= 1) {
        tsum += __shfl_xor(tsum, off, 64);
        trace += __shfl_xor(trace, off, 64);
        s1 += __shfl_xor(s1, off, 64);
        s2 += __shfl_xor(s2, off, 64);
        su += __shfl_xor(su, off, 64);
    }
    __shared__ float rr[16][5];
    if ((t & 63) == 0) {
        const int w = t >> 6;
        rr[w][0] = tsum; rr[w][1] = trace; rr[w][2] = s1;
        rr[w][3] = s2;   rr[w][4] = su;
    }
    __syncthreads();
    if (t == 0) {
        float a[5] = {0.f, 0.f, 0.f, 0.f, 0.f};
        for (int w = 0; w < 16; ++w)
#pragma unroll
            for (int q = 0; q < 5; ++q) a[q] += rr[w][q];
        const float reg = 1e-4f * (sqrtf(a[4]) + sqrtf(a[1]));
        const float loss = 0.5f * a[0] + 0.5f * a[3] - 2.0f * a[2] + reg;
        outp[0] = loss; outp[1] = reg; outp[2] = reg;
    }
}

extern "C" void kernel_launch(void* const* d_in, const int* in_sizes, int n_in,
                              void* d_out, int out_size, void* d_ws, size_t ws_size,
                              hipStream_t stream) {
    const int*   users    = (const int*)d_in[0];
    const int*   hist     = (const int*)d_in[1];
    const float* user_emb = (const float*)d_in[2];
    const float* item_emb = (const float*)d_in[3];
    const float* Hw       = (const float*)d_in[4];
    float* outp = (float*)d_out;
    float* ws   = (float*)d_ws;

    const int n_users = in_sizes[2] / 64;            // 200000
    const int n_items = in_sizes[3] / 64;            // 1000000
    const int batch   = in_sizes[0];                 // 4096
    const int histL   = in_sizes[1] / n_users;       // 200

    const unsigned npad = (unsigned)(((n_items + 1023) >> 10) << 10);
    const int nblk = (int)(npad >> 10);              // <= 1024 assumed (1M items)
    const int npairs = batch * histL;                // 819200

    int NA = 896;                                    // gram+pos blocks
    const int NSS = 96;                              // sumsq blocks
    const int NU  = 32;                              // user-gram blocks

    // ws layout (floats / aliased u32)
    size_t o = 0;
    auto alloc = [&](size_t n) { size_t r = o; o += (n + 15) & ~15ull; return r; };
    const size_t o_up     = alloc((size_t)batch * 64);
    const size_t o_counts = alloc(npad + 1);
    const size_t o_off    = alloc(npad + 1);
    const size_t o_cur    = alloc(npad + 1);
    const size_t o_btot   = alloc(nblk + 1);
    const size_t o_boff   = alloc(nblk + 2);
    const size_t o_vals   = alloc(npairs);
    const size_t o_ps1    = alloc(NA);
    const size_t o_ps2    = alloc(NA);
    const size_t o_pss    = alloc(NSS);
    const size_t o_part2  = alloc(8 * 6144);
    const size_t o_partB  = alloc((size_t)NU * 3072);
    const size_t o_partA  = o;                       // NA*3072, last
    long availf = (long)(ws_size / 4) - (long)o_partA;
    if ((long)NA * 3072 > availf) {
        NA = (int)(availf / 3072);
        if (NA < 8) NA = 8;
    }

    float*    Up      = ws + o_up;
    unsigned* counts  = (unsigned*)(ws + o_counts);
    unsigned* offsets = (unsigned*)(ws + o_off);
    unsigned* cursor  = (unsigned*)(ws + o_cur);
    unsigned* btot    = (unsigned*)(ws + o_btot);
    unsigned* boff    = (unsigned*)(ws + o_boff);
    unsigned* vals    = (unsigned*)(ws + o_vals);
    float*    partA   = ws + o_partA;
    float*    partB   = ws + o_partB;

    prep_kernel<<<1024, 256, 0, stream>>>(users, user_emb, Hw, batch, npad,
                                          Up, counts);
    hist_kernel<<<400, 256, 0, stream>>>(users, hist, batch, histL, counts);
    bsum_kernel<<<nblk, 256, 0, stream>>>(counts, btot);
    scan_kernel<<<1, 1024, 0, stream>>>(btot, nblk, boff);
    off_kernel<<<nblk, 256, 0, stream>>>(counts, boff, npad, offsets, cursor);
    scatter_kernel<<<400, 256, 0, stream>>>(users, hist, batch, histL,
                                            cursor, vals);
    fused_kernel<<<NA + NSS + NU, 256, 0, stream>>>(
        users, user_emb, item_emb, n_users, n_items, batch,
        NA, NSS, NU, offsets, vals, Up,
        partA, partB, ws + o_ps1, ws + o_ps2, ws + o_pss);
    reduce_gram_kernel<<<24 * 8, 256, 0, stream>>>(
        partA, NA, partB, NU, ws + o_part2);
    finalize_kernel<<<1, 1024, 0, stream>>>(
        ws + o_part2, Hw, ws + o_ps1, ws + o_ps2, NA,
        ws + o_pss, NSS, outp);
}

// Round 15
// 109.771 us; speedup vs baseline: 2.7868x; 2.7868x over previous
//
#include <hip/hip_runtime.h>
#include <hip/hip_bf16.h>

typedef __bf16 bf16x8 __attribute__((ext_vector_type(8)));
typedef float f32x16 __attribute__((ext_vector_type(16)));

// ---- Gram body: G = E^T E over [nrows x 64] (optional gather), bf16 MFMA ----
// Per-wave 16-row chunks, scalar column loads feeding 32x32x16 fragments
// directly, one-chunk register prefetch. Needs ~88 regs; keep VGPR cap >= 128.
template<bool GATHER>
static __device__ __forceinline__ void gram_body(
    const float* __restrict__ emb, const int* __restrict__ idx,
    int nrows, int nwaves_total, int blk,
    float* __restrict__ partial, float* __restrict__ red, int t) {
    const int lane = t & 63, wave = t >> 6;
    const int c = lane & 31, kh = lane >> 5;
    const int wid = blk * 4 + wave;
    const int step = nwaves_total * 16;

    f32x16 g00 = {}, g01 = {}, g11 = {};
    float cur0[8], cur1[8];

    int k0 = wid * 16;
    if (k0 < nrows) {
        const int kb = k0 + kh * 8;
#pragma unroll
        for (int j = 0; j < 8; ++j) {
            const size_t rb = (GATHER ? (size_t)idx[kb + j] : (size_t)(kb + j)) * 64;
            cur0[j] = emb[rb + c];
            cur1[j] = emb[rb + 32 + c];
        }
    }
    for (; k0 < nrows; k0 += step) {
        float nx0[8], nx1[8];
        const int k1 = k0 + step;
        if (k1 < nrows) {                       // prefetch next chunk
            const int kb = k1 + kh * 8;
#pragma unroll
            for (int j = 0; j < 8; ++j) {
                const size_t rb = (GATHER ? (size_t)idx[kb + j] : (size_t)(kb + j)) * 64;
                nx0[j] = emb[rb + c];
                nx1[j] = emb[rb + 32 + c];
            }
        } else {
#pragma unroll
            for (int j = 0; j < 8; ++j) { nx0[j] = 0.f; nx1[j] = 0.f; }
        }
        bf16x8 f0, f1;                          // nrows % 16 == 0 here
#pragma unroll
        for (int j = 0; j < 8; ++j) {
            f0[j] = (__bf16)cur0[j];
            f1[j] = (__bf16)cur1[j];
        }
        g00 = __builtin_amdgcn_mfma_f32_32x32x16_bf16(f0, f0, g00, 0, 0, 0);
        g01 = __builtin_amdgcn_mfma_f32_32x32x16_bf16(f0, f1, g01, 0, 0, 0);
        g11 = __builtin_amdgcn_mfma_f32_32x32x16_bf16(f1, f1, g11, 0, 0, 0);
#pragma unroll
        for (int j = 0; j < 8; ++j) { cur0[j] = nx0[j]; cur1[j] = nx1[j]; }
    }

    __syncthreads();
    for (int w = 0; w < 4; ++w) {
        if (wave == w) {
#pragma unroll
            for (int r = 0; r < 16; ++r) {
                const int cell = ((r & 3) + 8 * (r >> 2) + 4 * kh) * 32 + c;
                if (w == 0) {
                    red[cell] = g00[r]; red[1024 + cell] = g01[r]; red[2048 + cell] = g11[r];
                } else {
                    red[cell] += g00[r]; red[1024 + cell] += g01[r]; red[2048 + cell] += g11[r];
                }
            }
        }
        __syncthreads();
    }
    float* outp = partial + (size_t)blk * 3072;
    for (int i = t; i < 3072; i += 256) outp[i] = red[i];
}

// ---- fully fused heavy kernel ----------------------------------------------
// Grid = 1024 = 256 CU x 4 blocks -> all roles co-resident from t=0, no VGPR
// spill (cap 128 >= ~88 needed by gram). Proven best: R11, 110.2 us.
__global__ __launch_bounds__(256, 4) void fused_kernel(
    const int* __restrict__ users, const int* __restrict__ hist,
    const float* __restrict__ user_emb, const float* __restrict__ item_emb,
    const float* __restrict__ Hw,
    int n_users, int n_items, int batch, int histL,
    int NA, int NP, int NSS, int NU,
    float* __restrict__ partA, float* __restrict__ partB,
    float* __restrict__ p1, float* __restrict__ p2, float* __restrict__ pss) {
    __shared__ float red[3072];
    const int bid = blockIdx.x, t = threadIdx.x;

    if (bid < NA) {                              // ---- item gram role
        gram_body<false>(item_emb, nullptr, n_items, NA * 4, bid,
                         partA, red, t);
    } else if (bid < NA + NP) {                  // ---- pos role (grid-stride)
        const int pid = bid - NA;
        const int lane = t & 63, wave = t >> 6;
        const int k = lane & 15, g = lane >> 4;
        for (int w = pid * 4 + wave; w < batch; w += NP * 4) {
            const int iu = users[w];
            const float4 vu = *reinterpret_cast<const float4*>(user_emb + (size_t)iu * 64 + k * 4);
            const float4 vh = *reinterpret_cast<const float4*>(Hw + k * 4);
            const float4 uh = make_float4(vu.x * vh.x, vu.y * vh.y, vu.z * vh.z, vu.w * vh.w);
            const int* hrow = hist + (size_t)iu * histL;

            float s1 = 0.f, s2 = 0.f;
            int l = g;
            for (; l + 12 < histL; l += 16) {    // 4 groups x ILP-4
                int it[4];
#pragma unroll
                for (int u = 0; u < 4; ++u) it[u] = hrow[l + 4 * u];
                float d[4];
#pragma unroll
                for (int u = 0; u < 4; ++u) {
                    const float4 v = *reinterpret_cast<const float4*>(
                        item_emb + (size_t)it[u] * 64 + k * 4);
                    d[u] = v.x * uh.x + v.y * uh.y + v.z * uh.z + v.w * uh.w;
                }
#pragma unroll
                for (int u = 0; u < 4; ++u) {
                    float dd = d[u];
                    dd += __shfl_xor(dd, 1, 16);
                    dd += __shfl_xor(dd, 2, 16);
                    dd += __shfl_xor(dd, 4, 16);
                    dd += __shfl_xor(dd, 8, 16);
                    s1 += dd;                    // replicated x16; scaled below
                    s2 = fmaf(dd, dd, s2);
                }
            }
            for (; l < histL; l += 4) {
                const int it = hrow[l];
                const float4 v = *reinterpret_cast<const float4*>(
                    item_emb + (size_t)it * 64 + k * 4);
                float dd = v.x * uh.x + v.y * uh.y + v.z * uh.z + v.w * uh.w;
                dd += __shfl_xor(dd, 1, 16);
                dd += __shfl_xor(dd, 2, 16);
                dd += __shfl_xor(dd, 4, 16);
                dd += __shfl_xor(dd, 8, 16);
                s1 += dd;
                s2 = fmaf(dd, dd, s2);
            }
            s1 += __shfl_xor(s1, 16, 64); s1 += __shfl_xor(s1, 32, 64);
            s2 += __shfl_xor(s2, 16, 64); s2 += __shfl_xor(s2, 32, 64);
            if (lane == 0) { p1[w] = s1 * 0.0625f; p2[w] = s2 * 0.0625f; }
        }
    } else if (bid < NA + NP + NSS) {            // ---- sumsq role
        const int cid = bid - NA - NP;
        const int n4 = n_users * 16;
        float s = 0.f;
        for (int i = cid * 256 + t; i < n4; i += NSS * 256) {
            const float4 v = reinterpret_cast<const float4*>(user_emb)[i];
            s = fmaf(v.x, v.x, s); s = fmaf(v.y, v.y, s);
            s = fmaf(v.z, v.z, s); s = fmaf(v.w, v.w, s);
        }
#pragma unroll
        for (int off = 32; off >= 1; off >>= 1) s += __shfl_xor(s, off, 64);
        if ((t & 63) == 0) red[t >> 6] = s;
        __syncthreads();
        if (t == 0) pss[cid] = red[0] + red[1] + red[2] + red[3];
    } else {                                     // ---- user gram role
        gram_body<true>(user_emb, users, batch, NU * 4, bid - NA - NP - NSS,
                        partB, red, t);
    }
}

// ---- stage-1 reduce of gram partials, 8-way partial-dim split --------------
__global__ __launch_bounds__(256) void reduce_gram_kernel(
    const float* __restrict__ pa, int na,
    const float* __restrict__ pb, int nb, float* __restrict__ part2) {
    const int bid = blockIdx.x;
    const int cellblk = bid % 24, seg = bid / 24;
    const int e = cellblk * 256 + threadIdx.x;
    const float* p; int n, ee;
    if (e < 3072) { p = pa; n = na; ee = e; }
    else          { p = pb; n = nb; ee = e - 3072; }
    const int chunk = (n + 7) >> 3;
    const int b0 = seg * chunk;
    int b1 = b0 + chunk; if (b1 > n) b1 = n;
    float s[4] = {0.f, 0.f, 0.f, 0.f};
    int b = b0;
    for (; b + 4 <= b1; b += 4)
#pragma unroll
        for (int u = 0; u < 4; ++u) s[u] += p[(size_t)(b + u) * 3072 + ee];
    for (; b < b1; ++b) s[0] += p[(size_t)b * 3072 + ee];
    part2[(size_t)seg * 6144 + e] = (s[0] + s[1]) + (s[2] + s[3]);
}

// ---- finalize: 1024 threads, consumes part2 directly -----------------------
__global__ __launch_bounds__(1024) void finalize_kernel(
    const float* __restrict__ part2, const float* __restrict__ Hw,
    const float* __restrict__ p1, const float* __restrict__ p2, int npos,
    const float* __restrict__ pss, int nss, float* __restrict__ outp) {
    const int t = threadIdx.x;
    float tsum = 0.f, trace = 0.f, s1 = 0.f, s2 = 0.f, su = 0.f;
    for (int e = t; e < 3072; e += 1024) {
        float gi = 0.f, gu = 0.f;
#pragma unroll
        for (int seg = 0; seg < 8; ++seg) {
            gi += part2[(size_t)seg * 6144 + e];
            gu += part2[(size_t)seg * 6144 + 3072 + e];
        }
        const int tile = e >> 10, r = (e & 1023) >> 5, cc = e & 31;
        const int i = (tile == 2) ? r + 32 : r;
        const int j = (tile == 0) ? cc : cc + 32;
        const float w = (tile == 1) ? 2.0f : 1.0f;
        tsum += w * gi * gu * Hw[i] * Hw[j];
        if (i == j) trace += gi;
    }
    for (int e = t; e < npos; e += 1024) { s1 += p1[e]; s2 += p2[e]; }
    for (int e = t; e < nss; e += 1024) su += pss[e];
#pragma unroll
    for (int off = 32; off >= 1; off >>= 1) {
        tsum += __shfl_xor(tsum, off, 64);
        trace += __shfl_xor(trace, off, 64);
        s1 += __shfl_xor(s1, off, 64);
        s2 += __shfl_xor(s2, off, 64);
        su += __shfl_xor(su, off, 64);
    }
    __shared__ float rr[16][5];
    if ((t & 63) == 0) {
        const int w = t >> 6;
        rr[w][0] = tsum; rr[w][1] = trace; rr[w][2] = s1;
        rr[w][3] = s2;   rr[w][4] = su;
    }
    __syncthreads();
    if (t == 0) {
        float a[5] = {0.f, 0.f, 0.f, 0.f, 0.f};
        for (int w = 0; w < 16; ++w)
#pragma unroll
            for (int q = 0; q < 5; ++q) a[q] += rr[w][q];
        const float reg = 1e-4f * (sqrtf(a[4]) + sqrtf(a[1]));
        const float loss = 0.5f * a[0] + 0.5f * a[3] - 2.0f * a[2] + reg;
        outp[0] = loss; outp[1] = reg; outp[2] = reg;
    }
}

extern "C" void kernel_launch(void* const* d_in, const int* in_sizes, int n_in,
                              void* d_out, int out_size, void* d_ws, size_t ws_size,
                              hipStream_t stream) {
    const int*   users    = (const int*)d_in[0];
    const int*   hist     = (const int*)d_in[1];
    const float* user_emb = (const float*)d_in[2];
    const float* item_emb = (const float*)d_in[3];
    const float* Hw       = (const float*)d_in[4];
    float* outp = (float*)d_out;
    float* ws   = (float*)d_ws;

    const int n_users = in_sizes[2] / 64;            // 200000
    const int n_items = in_sizes[3] / 64;            // 1000000
    const int batch   = in_sizes[0];                 // 4096
    const int histL   = in_sizes[1] / n_users;       // 200

    // all-resident partition: 1024 blocks = 256 CU x 4 (no VGPR spill)
    int NA = 512;                                    // item-gram blocks
    const int NP  = 384;                             // pos blocks
    const int NSS = 96;                              // sumsq blocks
    const int NU  = 32;                              // user-gram blocks

    // ws layout (floats)
    const size_t o_p1 = 0;
    const size_t o_p2 = o_p1 + (size_t)batch;
    const size_t o_ss = o_p2 + (size_t)batch;
    const size_t o_part2 = o_ss + NSS;
    const size_t o_part = o_part2 + 8 * 6144;
    long availf = (long)(ws_size / 4) - (long)o_part - (long)NU * 3072;
    if ((long)NA * 3072 > availf) {
        NA = (int)(availf / 3072);
        if (NA < 8) NA = 8;
    }
    float* partA = ws + o_part;
    float* partB = partA + (size_t)NA * 3072;

    fused_kernel<<<NA + NP + NSS + NU, 256, 0, stream>>>(
        users, hist, user_emb, item_emb, Hw,
        n_users, n_items, batch, histL,
        NA, NP, NSS, NU,
        partA, partB, ws + o_p1, ws + o_p2, ws + o_ss);
    reduce_gram_kernel<<<24 * 8, 256, 0, stream>>>(
        partA, NA, partB, NU, ws + o_part2);
    finalize_kernel<<<1, 1024, 0, stream>>>(
        ws + o_part2, Hw, ws + o_p1, ws + o_p2, batch,
        ws + o_ss, NSS, outp);
}